// Round 3
// baseline (3671.079 us; speedup 1.0000x reference)
//
#include <hip/hip_runtime.h>

#define T_STEPS 2048
#define NBATCH  1024
#define HID     32

__device__ __forceinline__ float sigm(float v) {
    return __builtin_amdgcn_rcpf(1.0f + __expf(-v));
}
__device__ __forceinline__ float tanh_fast(float v) {
    float xc = fminf(fmaxf(v, -15.0f), 15.0f);
    float e  = __expf(-2.0f * xc);
    return (1.0f - e) * __builtin_amdgcn_rcpf(1.0f + e);
}
// wave-uniform read of lane `l`'s value (SGPR result)
__device__ __forceinline__ float rl(float v, int l) {
    return __uint_as_float((unsigned)__builtin_amdgcn_readlane(__float_as_uint(v), l));
}

// load one 32-float weight row into 8 named float4 registers
#define LOADW(pfx, base)                                                     \
    const float4* pfx##p = (const float4*)(base);                            \
    float4 pfx##0 = pfx##p[0], pfx##1 = pfx##p[1], pfx##2 = pfx##p[2],       \
           pfx##3 = pfx##p[3], pfx##4 = pfx##p[4], pfx##5 = pfx##p[5],       \
           pfx##6 = pfx##p[6], pfx##7 = pfx##p[7];

// 4 FMAs against persistent uniform array hs[] (constant indices)
#define FMAQ_S(acc, W_, hs, q)                                               \
    acc = fmaf((W_).x, hs[4*(q)+0], acc);                                    \
    acc = fmaf((W_).y, hs[4*(q)+1], acc);                                    \
    acc = fmaf((W_).z, hs[4*(q)+2], acc);                                    \
    acc = fmaf((W_).w, hs[4*(q)+3], acc);

// 4 FMAs against lane-replicated h via inline readlane
#define FMAQ_R(acc, W_, hv, q)                                               \
    acc = fmaf((W_).x, rl(hv, 4*(q)+0), acc);                                \
    acc = fmaf((W_).y, rl(hv, 4*(q)+1), acc);                                \
    acc = fmaf((W_).z, rl(hv, 4*(q)+2), acc);                                \
    acc = fmaf((W_).w, rl(hv, 4*(q)+3), acc);

// One block per batch element. 128 threads: thread g owns gate-row g of all
// three layers (i:0..31, f:32..63, g:64..95, o:96..127). Weights live in 160
// named-register floats. Gate pre-activations exchanged through triple-
// buffered LDS (1 barrier per layer); h vectors travel via v_readlane.
__global__ __launch_bounds__(128, 2)
void lstm3_fc_kernel(const float* __restrict__ x,
                     const float* __restrict__ Wih0, const float* __restrict__ Whh0,
                     const float* __restrict__ bih0, const float* __restrict__ bhh0,
                     const float* __restrict__ Wih1, const float* __restrict__ Whh1,
                     const float* __restrict__ bih1, const float* __restrict__ bhh1,
                     const float* __restrict__ Wih2, const float* __restrict__ Whh2,
                     const float* __restrict__ bih2, const float* __restrict__ bhh2,
                     const float* __restrict__ Wfc,  const float* __restrict__ bfc,
                     float* __restrict__ out)
{
    const int g = threadIdx.x;   // 0..127
    const int b = blockIdx.x;    // 0..1023

    LOADW(w0_, Whh0 + g * HID)   // layer0 Whh row g
    LOADW(w1_, Wih1 + g * HID)   // layer1 Wih row g
    LOADW(w2_, Whh1 + g * HID)   // layer1 Whh row g
    LOADW(w3_, Wih2 + g * HID)   // layer2 Wih row g
    LOADW(w4_, Whh2 + g * HID)   // layer2 Whh row g

    const float wih0g = Wih0[g];               // Wih0 is (128,1)
    const float bias0 = bih0[g] + bhh0[g];
    const float bias1 = bih1[g] + bhh1[g];
    const float bias2 = bih2[g] + bhh2[g];
    const float wfcg  = Wfc[g & 31];
    const float bfc0  = bfc[0];

    __shared__ float GT0[128], GT1[128], GT2[128];

    float h0s[32];
#pragma unroll
    for (int k = 0; k < 32; ++k) h0s[k] = 0.0f;   // persistent uniforms (h0)
    float h1v = 0.0f, h2v = 0.0f;                 // lane-replicated h1, h2
    float c0 = 0.0f, c1 = 0.0f, c2 = 0.0f;        // cell state of unit g&31

    float xt = x[b];
    for (int t = 0; t < T_STEPS; ++t) {
        const int tn = (t + 1 < T_STEPS) ? (t + 1) : t;
        const float xnext = x[tn * NBATCH + b];   // prefetch

        // ---------- layer 0 gates: Wih0*x + Whh0 @ h0(old) ----------
        float a0 = fmaf(wih0g, xt, bias0), a1 = 0.f, a2 = 0.f, a3 = 0.f;
        FMAQ_S(a0, w0_0, h0s, 0) FMAQ_S(a1, w0_1, h0s, 1)
        FMAQ_S(a2, w0_2, h0s, 2) FMAQ_S(a3, w0_3, h0s, 3)
        FMAQ_S(a0, w0_4, h0s, 4) FMAQ_S(a1, w0_5, h0s, 5)
        FMAQ_S(a2, w0_6, h0s, 6) FMAQ_S(a3, w0_7, h0s, 7)
        GT0[g] = (a0 + a1) + (a2 + a3);
        __syncthreads();
        float h0v;
        {   const int j = g & 31;
            float ii = sigm(GT0[j]);
            float ff = sigm(GT0[j + 32]);
            float gg = tanh_fast(GT0[j + 64]);
            float oo = sigm(GT0[j + 96]);
            c0 = fmaf(ff, c0, ii * gg);
            h0v = oo * tanh_fast(c0);
        }
#pragma unroll
        for (int k = 0; k < 32; ++k) h0s[k] = rl(h0v, k);  // h0 -> uniforms

        // ---------- layer 1 gates: Wih1 @ h0(new) + Whh1 @ h1(old) ----------
        a0 = bias1; a1 = 0.f; a2 = 0.f; a3 = 0.f;
        FMAQ_S(a0, w1_0, h0s, 0) FMAQ_S(a1, w1_1, h0s, 1)
        FMAQ_S(a2, w1_2, h0s, 2) FMAQ_S(a3, w1_3, h0s, 3)
        FMAQ_S(a0, w1_4, h0s, 4) FMAQ_S(a1, w1_5, h0s, 5)
        FMAQ_S(a2, w1_6, h0s, 6) FMAQ_S(a3, w1_7, h0s, 7)
        FMAQ_R(a0, w2_0, h1v, 0) FMAQ_R(a1, w2_1, h1v, 1)
        FMAQ_R(a2, w2_2, h1v, 2) FMAQ_R(a3, w2_3, h1v, 3)
        FMAQ_R(a0, w2_4, h1v, 4) FMAQ_R(a1, w2_5, h1v, 5)
        FMAQ_R(a2, w2_6, h1v, 6) FMAQ_R(a3, w2_7, h1v, 7)
        GT1[g] = (a0 + a1) + (a2 + a3);
        __syncthreads();
        {   const int j = g & 31;
            float ii = sigm(GT1[j]);
            float ff = sigm(GT1[j + 32]);
            float gg = tanh_fast(GT1[j + 64]);
            float oo = sigm(GT1[j + 96]);
            c1 = fmaf(ff, c1, ii * gg);
            h1v = oo * tanh_fast(c1);   // new h1
        }

        // ---------- layer 2 gates: Wih2 @ h1(new) + Whh2 @ h2(old) ----------
        a0 = bias2; a1 = 0.f; a2 = 0.f; a3 = 0.f;
        FMAQ_R(a0, w3_0, h1v, 0) FMAQ_R(a1, w3_1, h1v, 1)
        FMAQ_R(a2, w3_2, h1v, 2) FMAQ_R(a3, w3_3, h1v, 3)
        FMAQ_R(a0, w3_4, h1v, 4) FMAQ_R(a1, w3_5, h1v, 5)
        FMAQ_R(a2, w3_6, h1v, 6) FMAQ_R(a3, w3_7, h1v, 7)
        FMAQ_R(a0, w4_0, h2v, 0) FMAQ_R(a1, w4_1, h2v, 1)
        FMAQ_R(a2, w4_2, h2v, 2) FMAQ_R(a3, w4_3, h2v, 3)
        FMAQ_R(a0, w4_4, h2v, 4) FMAQ_R(a1, w4_5, h2v, 5)
        FMAQ_R(a2, w4_6, h2v, 6) FMAQ_R(a3, w4_7, h2v, 7)
        GT2[g] = (a0 + a1) + (a2 + a3);
        __syncthreads();
        {   const int j = g & 31;
            float ii = sigm(GT2[j]);
            float ff = sigm(GT2[j + 32]);
            float gg = tanh_fast(GT2[j + 64]);
            float oo = sigm(GT2[j + 96]);
            c2 = fmaf(ff, c2, ii * gg);
            h2v = oo * tanh_fast(c2);   // new h2
        }

        // ---------- fused FC: out[t][b] = Wfc @ h2 + bfc ----------
        float v = wfcg * h2v;
        v += __shfl_xor(v, 16);
        v += __shfl_xor(v, 8);
        v += __shfl_xor(v, 4);
        v += __shfl_xor(v, 2);
        v += __shfl_xor(v, 1);
        if (g == 0) out[t * NBATCH + b] = v + bfc0;

        xt = xnext;
    }
}

extern "C" void kernel_launch(void* const* d_in, const int* in_sizes, int n_in,
                              void* d_out, int out_size, void* d_ws, size_t ws_size,
                              hipStream_t stream)
{
    const float* x    = (const float*)d_in[0];
    const float* Wih0 = (const float*)d_in[1];
    const float* Whh0 = (const float*)d_in[2];
    const float* bih0 = (const float*)d_in[3];
    const float* bhh0 = (const float*)d_in[4];
    const float* Wih1 = (const float*)d_in[5];
    const float* Whh1 = (const float*)d_in[6];
    const float* bih1 = (const float*)d_in[7];
    const float* bhh1 = (const float*)d_in[8];
    const float* Wih2 = (const float*)d_in[9];
    const float* Whh2 = (const float*)d_in[10];
    const float* bih2 = (const float*)d_in[11];
    const float* bhh2 = (const float*)d_in[12];
    const float* Wfc  = (const float*)d_in[13];
    const float* bfc  = (const float*)d_in[14];
    float* out        = (float*)d_out;

    lstm3_fc_kernel<<<dim3(NBATCH), dim3(128), 0, stream>>>(
        x, Wih0, Whh0, bih0, bhh0,
        Wih1, Whh1, bih1, bhh1,
        Wih2, Whh2, bih2, bhh2,
        Wfc, bfc, out);
}

// Round 4
// 3657.004 us; speedup vs baseline: 1.0038x; 1.0038x over previous
//
#include <hip/hip_runtime.h>

#define T_STEPS 2048
#define NBATCH  1024
#define HID     32

__device__ __forceinline__ float sigm(float v) {
    return __builtin_amdgcn_rcpf(1.0f + __expf(-v));
}
__device__ __forceinline__ float tanh_fast(float v) {
    float xc = fminf(fmaxf(v, -15.0f), 15.0f);
    float e  = __expf(-2.0f * xc);
    return (1.0f - e) * __builtin_amdgcn_rcpf(1.0f + e);
}
// wave-uniform read of lane `l`'s value (SGPR result)
__device__ __forceinline__ float rl(float v, int l) {
    return __uint_as_float((unsigned)__builtin_amdgcn_readlane(__float_as_uint(v), l));
}

// load one 32-float weight row into 8 named float4 registers
#define LOADW(pfx, base)                                                     \
    const float4* pfx##p = (const float4*)(base);                            \
    float4 pfx##0 = pfx##p[0], pfx##1 = pfx##p[1], pfx##2 = pfx##p[2],       \
           pfx##3 = pfx##p[3], pfx##4 = pfx##p[4], pfx##5 = pfx##p[5],       \
           pfx##6 = pfx##p[6], pfx##7 = pfx##p[7];

// Pin a float4's components into VGPRs: opaque-origin => compiler cannot
// rematerialize the global load inside the T-loop, must keep values resident.
#define PIN4(v4)                                                             \
    asm volatile("" : "+v"((v4).x), "+v"((v4).y), "+v"((v4).z), "+v"((v4).w));
#define PINROW(pfx)                                                          \
    PIN4(pfx##0) PIN4(pfx##1) PIN4(pfx##2) PIN4(pfx##3)                      \
    PIN4(pfx##4) PIN4(pfx##5) PIN4(pfx##6) PIN4(pfx##7)

// 4 FMAs against persistent uniform array hs[] (constant indices)
#define FMAQ_S(acc, W_, hs, q)                                               \
    acc = fmaf((W_).x, hs[4*(q)+0], acc);                                    \
    acc = fmaf((W_).y, hs[4*(q)+1], acc);                                    \
    acc = fmaf((W_).z, hs[4*(q)+2], acc);                                    \
    acc = fmaf((W_).w, hs[4*(q)+3], acc);

// 4 FMAs against lane-replicated h via inline readlane
#define FMAQ_R(acc, W_, hv, q)                                               \
    acc = fmaf((W_).x, rl(hv, 4*(q)+0), acc);                                \
    acc = fmaf((W_).y, rl(hv, 4*(q)+1), acc);                                \
    acc = fmaf((W_).z, rl(hv, 4*(q)+2), acc);                                \
    acc = fmaf((W_).w, rl(hv, 4*(q)+3), acc);

// One block per batch element. 128 threads: thread g owns gate-row g of all
// three layers (i:0..31, f:32..63, g:64..95, o:96..127). Weights pinned in
// 160 VGPRs via asm laundering. Gate pre-activations exchanged through LDS
// (1 barrier per layer); h vectors travel via v_readlane.
__global__ __launch_bounds__(128, 2)
void lstm3_fc_kernel(const float* __restrict__ x,
                     const float* __restrict__ Wih0, const float* __restrict__ Whh0,
                     const float* __restrict__ bih0, const float* __restrict__ bhh0,
                     const float* __restrict__ Wih1, const float* __restrict__ Whh1,
                     const float* __restrict__ bih1, const float* __restrict__ bhh1,
                     const float* __restrict__ Wih2, const float* __restrict__ Whh2,
                     const float* __restrict__ bih2, const float* __restrict__ bhh2,
                     const float* __restrict__ Wfc,  const float* __restrict__ bfc,
                     float* __restrict__ out)
{
    const int g = threadIdx.x;   // 0..127
    const int b = blockIdx.x;    // 0..1023

    LOADW(w0_, Whh0 + g * HID)   // layer0 Whh row g
    LOADW(w1_, Wih1 + g * HID)   // layer1 Wih row g
    LOADW(w2_, Whh1 + g * HID)   // layer1 Whh row g
    LOADW(w3_, Wih2 + g * HID)   // layer2 Wih row g
    LOADW(w4_, Whh2 + g * HID)   // layer2 Whh row g
    PINROW(w0_) PINROW(w1_) PINROW(w2_) PINROW(w3_) PINROW(w4_)

    const float wih0g = Wih0[g];               // Wih0 is (128,1)
    const float bias0 = bih0[g] + bhh0[g];
    const float bias1 = bih1[g] + bhh1[g];
    const float bias2 = bih2[g] + bhh2[g];
    const float wfcg  = Wfc[g & 31];
    const float bfc0  = bfc[0];

    __shared__ float GT0[128], GT1[128], GT2[128];

    float h0s[32];
#pragma unroll
    for (int k = 0; k < 32; ++k) h0s[k] = 0.0f;   // persistent uniforms (h0)
    float h1v = 0.0f, h2v = 0.0f;                 // lane-replicated h1, h2
    float c0 = 0.0f, c1 = 0.0f, c2 = 0.0f;        // cell state of unit g&31

    float xt = x[b];
    for (int t = 0; t < T_STEPS; ++t) {
        const int tn = (t + 1 < T_STEPS) ? (t + 1) : t;
        const float xnext = x[tn * NBATCH + b];   // prefetch

        // ---------- layer 0 gates: Wih0*x + Whh0 @ h0(old) ----------
        float a0 = fmaf(wih0g, xt, bias0), a1 = 0.f, a2 = 0.f, a3 = 0.f;
        FMAQ_S(a0, w0_0, h0s, 0) FMAQ_S(a1, w0_1, h0s, 1)
        FMAQ_S(a2, w0_2, h0s, 2) FMAQ_S(a3, w0_3, h0s, 3)
        FMAQ_S(a0, w0_4, h0s, 4) FMAQ_S(a1, w0_5, h0s, 5)
        FMAQ_S(a2, w0_6, h0s, 6) FMAQ_S(a3, w0_7, h0s, 7)
        GT0[g] = (a0 + a1) + (a2 + a3);
        __syncthreads();
        float h0v;
        {   const int j = g & 31;
            float ii = sigm(GT0[j]);
            float ff = sigm(GT0[j + 32]);
            float gg = tanh_fast(GT0[j + 64]);
            float oo = sigm(GT0[j + 96]);
            c0 = fmaf(ff, c0, ii * gg);
            h0v = oo * tanh_fast(c0);
        }
#pragma unroll
        for (int k = 0; k < 32; ++k) h0s[k] = rl(h0v, k);  // h0 -> uniforms

        // ---------- layer 1 gates: Wih1 @ h0(new) + Whh1 @ h1(old) ----------
        a0 = bias1; a1 = 0.f; a2 = 0.f; a3 = 0.f;
        FMAQ_S(a0, w1_0, h0s, 0) FMAQ_S(a1, w1_1, h0s, 1)
        FMAQ_S(a2, w1_2, h0s, 2) FMAQ_S(a3, w1_3, h0s, 3)
        FMAQ_S(a0, w1_4, h0s, 4) FMAQ_S(a1, w1_5, h0s, 5)
        FMAQ_S(a2, w1_6, h0s, 6) FMAQ_S(a3, w1_7, h0s, 7)
        FMAQ_R(a0, w2_0, h1v, 0) FMAQ_R(a1, w2_1, h1v, 1)
        FMAQ_R(a2, w2_2, h1v, 2) FMAQ_R(a3, w2_3, h1v, 3)
        FMAQ_R(a0, w2_4, h1v, 4) FMAQ_R(a1, w2_5, h1v, 5)
        FMAQ_R(a2, w2_6, h1v, 6) FMAQ_R(a3, w2_7, h1v, 7)
        GT1[g] = (a0 + a1) + (a2 + a3);
        __syncthreads();
        {   const int j = g & 31;
            float ii = sigm(GT1[j]);
            float ff = sigm(GT1[j + 32]);
            float gg = tanh_fast(GT1[j + 64]);
            float oo = sigm(GT1[j + 96]);
            c1 = fmaf(ff, c1, ii * gg);
            h1v = oo * tanh_fast(c1);   // new h1
        }

        // ---------- layer 2 gates: Wih2 @ h1(new) + Whh2 @ h2(old) ----------
        a0 = bias2; a1 = 0.f; a2 = 0.f; a3 = 0.f;
        FMAQ_R(a0, w3_0, h1v, 0) FMAQ_R(a1, w3_1, h1v, 1)
        FMAQ_R(a2, w3_2, h1v, 2) FMAQ_R(a3, w3_3, h1v, 3)
        FMAQ_R(a0, w3_4, h1v, 4) FMAQ_R(a1, w3_5, h1v, 5)
        FMAQ_R(a2, w3_6, h1v, 6) FMAQ_R(a3, w3_7, h1v, 7)
        FMAQ_R(a0, w4_0, h2v, 0) FMAQ_R(a1, w4_1, h2v, 1)
        FMAQ_R(a2, w4_2, h2v, 2) FMAQ_R(a3, w4_3, h2v, 3)
        FMAQ_R(a0, w4_4, h2v, 4) FMAQ_R(a1, w4_5, h2v, 5)
        FMAQ_R(a2, w4_6, h2v, 6) FMAQ_R(a3, w4_7, h2v, 7)
        GT2[g] = (a0 + a1) + (a2 + a3);
        __syncthreads();
        {   const int j = g & 31;
            float ii = sigm(GT2[j]);
            float ff = sigm(GT2[j + 32]);
            float gg = tanh_fast(GT2[j + 64]);
            float oo = sigm(GT2[j + 96]);
            c2 = fmaf(ff, c2, ii * gg);
            h2v = oo * tanh_fast(c2);   // new h2
        }

        // ---------- fused FC: out[t][b] = Wfc @ h2 + bfc ----------
        float v = wfcg * h2v;
        v += __shfl_xor(v, 16);
        v += __shfl_xor(v, 8);
        v += __shfl_xor(v, 4);
        v += __shfl_xor(v, 2);
        v += __shfl_xor(v, 1);
        if (g == 0) out[t * NBATCH + b] = v + bfc0;

        xt = xnext;
    }
}

extern "C" void kernel_launch(void* const* d_in, const int* in_sizes, int n_in,
                              void* d_out, int out_size, void* d_ws, size_t ws_size,
                              hipStream_t stream)
{
    const float* x    = (const float*)d_in[0];
    const float* Wih0 = (const float*)d_in[1];
    const float* Whh0 = (const float*)d_in[2];
    const float* bih0 = (const float*)d_in[3];
    const float* bhh0 = (const float*)d_in[4];
    const float* Wih1 = (const float*)d_in[5];
    const float* Whh1 = (const float*)d_in[6];
    const float* bih1 = (const float*)d_in[7];
    const float* bhh1 = (const float*)d_in[8];
    const float* Wih2 = (const float*)d_in[9];
    const float* Whh2 = (const float*)d_in[10];
    const float* bih2 = (const float*)d_in[11];
    const float* bhh2 = (const float*)d_in[12];
    const float* Wfc  = (const float*)d_in[13];
    const float* bfc  = (const float*)d_in[14];
    float* out        = (float*)d_out;

    lstm3_fc_kernel<<<dim3(NBATCH), dim3(128), 0, stream>>>(
        x, Wih0, Whh0, bih0, bhh0,
        Wih1, Whh1, bih1, bhh1,
        Wih2, Whh2, bih2, bhh2,
        Wfc, bfc, out);
}